// Round 1
// baseline (3458.810 us; speedup 1.0000x reference)
//
#include <hip/hip_runtime.h>
#include <math.h>

// Problem constants
#define TLEN    960000          // samples per batch
#define BATCH   16
#define KF      144000          // filter length (KP taps + appended 1.0)
#define KP      143999          // ir_param length
#define HRPL    145536          // per shifted filter copy: 512 front pad + KF + back pad
#define NI      1104896         // padded x row length; covers max A prefetch read 1,104,887
#define NTILE   938             // ceil(960000 / 1024) output tiles of 1024
#define QCH     1128            // chunks per K-quarter (4*1128*32 = KF+384 band)
#define NGQ     47              // groups per quarter (24 chunks each)
#define GCH     24              // chunks per group
#define CPYSTR  1552            // LDS filter copy stride (elems) = 1536 + 16 pad (bank spread)
#define FBUFE   12416           // one F staging buffer: 8 copies * 1552 elems
#define W0OFF   256             // window start = 32*C0 + 256

typedef __attribute__((ext_vector_type(8))) short bf16x8;
typedef __attribute__((ext_vector_type(16))) float f32x16;

__device__ __forceinline__ unsigned short f2bf(float f) {
  unsigned int u = __float_as_uint(f);
  u += 0x7FFFu + ((u >> 16) & 1u);   // RNE
  return (unsigned short)(u >> 16);
}

// async global->LDS, 16B per lane: LDS dest = uniform base + lane*16 (m104/m108)
__device__ __forceinline__ void gl_lds16(const unsigned short* g, unsigned short* l) {
  __builtin_amdgcn_global_load_lds((const __attribute__((address_space(1))) void*)g,
                                   (__attribute__((address_space(3))) void*)l, 16, 0, 0);
}

// 8 shifted copies of reversed filter hrp[m][i] = hrval(i-512-m).
// IDENTITY SPLIT: the t==KP tap (the appended 1.0) is EXCLUDED here; init_out_kernel
// adds it exactly in fp32 (out = x). The MFMA path only computes the reverb tail
// (|h| <= ~4e-6), so bf16 rounding error collapses (absmax ~0.03 -> ~1e-4).
__global__ __launch_bounds__(256) void build_hrp_kernel(const float* __restrict__ irp,
                                                        unsigned short* __restrict__ hrp) {
  int idx = blockIdx.x * 256 + threadIdx.x;
  if (idx >= 8 * HRPL) return;
  int m = idx / HRPL;
  int i = idx - m * HRPL;
  int t = i - 512 - m;
  unsigned short v = 0;
  if (t >= 0 && t < KP) v = f2bf(tanhf(irp[t]));
  hrp[idx] = v;
}

// Chunk-major bf16 x: xbp2[u*128 + b*8 + j] = xpad(b, 8u+j), xpad(b,i) = x[b][i-KF] or 0.
__global__ __launch_bounds__(256) void build_xbp2_kernel(const float* __restrict__ x,
                                                         unsigned short* __restrict__ xbp2) {
  int idx = blockIdx.x * 256 + threadIdx.x;
  if (idx >= NI * BATCH) return;
  int u = idx >> 7;
  int r = idx & 127;
  int b = r >> 3;
  int j = idx & 7;
  int i = (u << 3) | j;
  float v = 0.f;
  int s = i - KF;
  if (s >= 0 && s < TLEN) v = x[b * TLEN + s];
  xbp2[idx] = f2bf(v);
}

// out = x exactly (identity tap in fp32); conv adds reverb partials on top.
__global__ __launch_bounds__(256) void init_out_kernel(const float4* __restrict__ x4,
                                                       float4* __restrict__ out4) {
  int idx = blockIdx.x * 256 + threadIdx.x;   // 15,000*256 = 3,840,000 = exactly out/4
  out4[idx] = x4[idx];
}

// 32x32x16 restructure. Block = 4 waves = 4 adjacent 256-output tiles, SAME K-quarter.
// Wave's 256 outputs = 4 D-tiles d of 32x32: D_d[row][col], col=t (32 outputs),
// row=(h,b): out index O = Twave + 32d + t + 128h.  Per K-step s (16 taps):
//   A_d[(h,b)][k] = xpad(b, Twave + 32C + 32d + 128h + 16s + k)   (k = 8e+j, e=lane>>5)
//   B_s[k][t]     = hrval(32C + 16s + k - t - 1)                  (t = lane&31)
// B is INDEPENDENT of d -> one B fragment feeds all 4 tiles; per chunk (32 taps):
// 8 MFMAs, 2 ds_read_b128 (B, 1-chunk-ahead 4-slot ring), 2 global 16B (A 12-slot
// ring, 2-chunk-ahead).  MFMA pipe cycles/chunk: 8*8.07 = 64.6 vs old 16*4.85 = 77.6.
__global__ __launch_bounds__(256, 3) void conv_main_kernel(const unsigned short* __restrict__ xbp2,
                                                           const unsigned short* __restrict__ hrp,
                                                           float* __restrict__ out) {
  const int tid  = threadIdx.x;
  const int wv   = tid >> 6;
  const int lane = tid & 63;
  const int t32  = lane & 31;       // B/D column
  const int e    = lane >> 5;       // K-half (A/B), D row bit2
  const int hA   = (lane >> 4) & 1; // A row bit4 (output-half)
  const int bA   = lane & 15;       // A row batch

  const int bid  = blockIdx.x;
  const int Q    = bid / NTILE;          // K-quarter 0..3
  const int tile = bid - Q * NTILE;      // output tile 0..937
  const int C0   = Q * QCH;              // first absolute chunk of this quarter

  const int Twave = tile * 1024 + wv * 256;

  // ---- A addressing (chunk-major xbp2): position p = Twave+32*C0+128hA+8e (mult of 8)
  // elem = (p>>3)*128 + bA*8 ; fragment mu at +mu*256 elems ; chunk advance = +512 elems
  const unsigned short* aB = xbp2 + ((Twave + 32 * C0 + 128 * hA + 8 * e) >> 3) * 128 + bA * 8;

  // ---- F lane constants. Copy m = (-E0)&7 => (E0+m) % 8 == 0 (true 16B alignment).
  const int E0 = 511 - t32 + 8 * e;
  const int m  = (-E0) & 7;
  const int fo = m * CPYSTR + (E0 + m - W0OFF);   // in-copy elem range [224,270] (<1536 ok)

  __shared__ unsigned short fbuf[2 * FBUFE];      // 49,664 B

  // ---- stage group 0 (wave wv stages copies 2wv, 2wv+1; 3 x 512 elems each)
  const int j0 = 2 * wv, j1 = 2 * wv + 1;
  {
    const int W = C0 * 32 + W0OFF;
#pragma unroll
    for (int h = 0; h < 3; ++h) {
      gl_lds16(hrp + j0 * HRPL + W + h * 512 + lane * 8, fbuf + j0 * CPYSTR + h * 512);
      gl_lds16(hrp + j1 * HRPL + W + h * 512 + lane * 8, fbuf + j1 * CPYSTR + h * 512);
    }
  }

  // ---- A ring preload: fragments mu = 0..11 (slot = mu % 12); prefetch ptr at mu=10
  bf16x8 R[12];
#pragma unroll
  for (int u = 0; u < 12; ++u) R[u] = *(const bf16x8*)(aB + u * 256);
  const unsigned short* aPp = aB + 2560;   // chunk-c prefetch loads mu_abs = 2c+10, 2c+11

  __syncthreads();   // buffer 0 staged

  // ---- B ring preload: chunk 0 fragments (slots 0,1); slots 2,3 filled by chunk 0
  bf16x8 BF[4];
  {
    const unsigned short* fb0 = fbuf + fo;
    BF[0] = *(const bf16x8*)(fb0);
    BF[1] = *(const bf16x8*)(fb0 + 16);
  }

  f32x16 acc[4] = {};

  for (int g = 0; g < NGQ; ++g) {
    if (g < NGQ - 1) {   // stage group g+1 into the other buffer (async)
      const int W = C0 * 32 + W0OFF + (g + 1) * 768;
      unsigned short* db = fbuf + ((g + 1) & 1) * FBUFE;
#pragma unroll
      for (int h = 0; h < 3; ++h) {
        gl_lds16(hrp + j0 * HRPL + W + h * 512 + lane * 8, db + j0 * CPYSTR + h * 512);
        gl_lds16(hrp + j1 * HRPL + W + h * 512 + lane * 8, db + j1 * CPYSTR + h * 512);
      }
    }
    const unsigned short* fbL = fbuf + (g & 1) * FBUFE + fo;
#pragma unroll
    for (int c = 0; c < GCH; ++c) {
      // B prefetch for chunk c+1 (c=23 reads next group's chunk 0 from SAME buffer:
      // offsets 768..816+ < 1536 -> staged copy spans 2 group-advances, valid)
      BF[(2 * c + 2) & 3] = *(const bf16x8*)(fbL + 32 * (c + 1));
      BF[(2 * c + 3) & 3] = *(const bf16x8*)(fbL + 32 * (c + 1) + 16);
      // A prefetch: mu_abs = 2C+10, 2C+11 -> first used 2 chunks later (~2-chunk dist)
      R[(2 * c + 10) % 12] = *(const bf16x8*)(aPp);
      R[(2 * c + 11) % 12] = *(const bf16x8*)(aPp + 256);
      aPp += 512;
      const bf16x8 b0 = BF[(2 * c) & 3];       // step s=0 (loaded last chunk)
      const bf16x8 b1 = BF[(2 * c + 1) & 3];   // step s=1
      // 4 D-tiles x 2 K-steps; A slot for (d,s) = (2C + 2d + s) % 12
      acc[0] = __builtin_amdgcn_mfma_f32_32x32x16_bf16(R[(2*c+0)%12], b0, acc[0], 0,0,0);
      acc[0] = __builtin_amdgcn_mfma_f32_32x32x16_bf16(R[(2*c+1)%12], b1, acc[0], 0,0,0);
      acc[1] = __builtin_amdgcn_mfma_f32_32x32x16_bf16(R[(2*c+2)%12], b0, acc[1], 0,0,0);
      acc[1] = __builtin_amdgcn_mfma_f32_32x32x16_bf16(R[(2*c+3)%12], b1, acc[1], 0,0,0);
      acc[2] = __builtin_amdgcn_mfma_f32_32x32x16_bf16(R[(2*c+4)%12], b0, acc[2], 0,0,0);
      acc[2] = __builtin_amdgcn_mfma_f32_32x32x16_bf16(R[(2*c+5)%12], b1, acc[2], 0,0,0);
      acc[3] = __builtin_amdgcn_mfma_f32_32x32x16_bf16(R[(2*c+6)%12], b0, acc[3], 0,0,0);
      acc[3] = __builtin_amdgcn_mfma_f32_32x32x16_bf16(R[(2*c+7)%12], b1, acc[3], 0,0,0);
    }
    __syncthreads();   // drains this wave's stage(g+1) + all waves done reading buf g
  }

  // ---- epilogue: accumulate quarter partial into out (pre-initialized to x).
  // D: col = t32, row = (r&3) + 8*(r>>2) + 4*e  ->  b = row&15, h = row>>4 (= r>>3)
#pragma unroll
  for (int d = 0; d < 4; ++d) {
#pragma unroll
    for (int r = 0; r < 16; ++r) {
      const int row = (r & 3) + 8 * (r >> 2) + 4 * e;
      const int b = row & 15;
      const int h = row >> 4;
      const int t = Twave + 32 * d + t32 + 128 * h;
      if (t < TLEN) atomicAdd(&out[b * TLEN + t], acc[d][r]);
    }
  }
}

extern "C" void kernel_launch(void* const* d_in, const int* in_sizes, int n_in,
                              void* d_out, int out_size, void* d_ws, size_t ws_size,
                              hipStream_t stream) {
  const float* x   = (const float*)d_in[0];   // (16,1,960000) f32
  const float* irp = (const float*)d_in[1];   // (1,1,143999) f32
  float* out = (float*)d_out;                 // (16,1,960000) f32

  // ws: [ hrp: 8*HRPL bf16 = 2,328,576 B | xbp2: NI*16 bf16 = 35,356,672 B ] = 37.69 MB
  unsigned short* hrp  = (unsigned short*)d_ws;
  unsigned short* xbp2 = (unsigned short*)((char*)d_ws + (size_t)(8 * HRPL) * 2);

  build_hrp_kernel<<<(8 * HRPL + 255) / 256, 256, 0, stream>>>(irp, hrp);
  build_xbp2_kernel<<<(NI * BATCH + 255) / 256, 256, 0, stream>>>(x, xbp2);
  init_out_kernel<<<15000, 256, 0, stream>>>((const float4*)x, (float4*)out);
  // 938 tiles x 4 K-quarters; block = 4 waves = 4 adjacent 256-output tiles
  conv_main_kernel<<<NTILE * 4, 256, 0, stream>>>(xbp2, hrp, out);
}